// Round 1
// baseline (271.387 us; speedup 1.0000x reference)
//
#include <hip/hip_runtime.h>

// SimpleRNN, hidden=1: h_t = tanh(a*x_t + b*h_{t-1} + c), out = h_T per row.
// B=8192 independent serial chains of length T=4096 -> latency-bound.
//
// Critical-chain minimization: track E_t = exp(2*t_t) instead of h_t:
//   r_t   = rcp(E_t + 1)                      (h_t = 1 - 2*r_t)
//   u_t+1 = q_{t+1} - B4 * r_t                (fma; q is off-chain)
//   E_t+1 = exp2(u_{t+1})
// with q_t = 2*log2e*(b + c + a*x_t), B4 = 4*b*log2e.
// On-chain per step: v_add, v_rcp, v_fma, v_exp  (~24 cyc dependent chain).

constexpr int T_LEN = 4096;
constexpr int NPF   = 16;                 // float4 prefetch ring -> 64-step lookahead
constexpr int NBLK  = T_LEN / 4 / NPF;    // 64 outer iterations

__global__ __launch_bounds__(64, 1)
void rnn_scan_kernel(const float* __restrict__ x,
                     const float* __restrict__ w_ih,
                     const float* __restrict__ w_hh,
                     const float* __restrict__ b_ih,
                     const float* __restrict__ b_hh,
                     float* __restrict__ out) {
    const int row = blockIdx.x * 64 + threadIdx.x;

    // Scalars (uniform; cached broadcast loads)
    const float a  = w_ih[0];
    const float bb = w_hh[0];
    const float c  = b_ih[0] + b_hh[0];

    const float L2E2 = 2.88539008177792681472f;   // 2*log2(e)
    const float A2   = a * L2E2;                  // q = fma(x, A2, C2)
    const float C2   = (bb + c) * L2E2;
    const float nB4  = -(bb * L2E2 * 2.0f);       // -4*b*log2(e)

    const float4* xp = (const float4*)(x + (size_t)row * T_LEN);

    // Prefetch ring: 16 x float4 = 64 steps ahead (~1.5K cycles > HBM latency)
    float4 buf[NPF];
#pragma unroll
    for (int i = 0; i < NPF; ++i) buf[i] = xp[i];

    float E = 1.0f;  // corresponds to h_0 = 0  (r = 0.5 folds exactly into C2 term)

    for (int blk = 0; blk < NBLK; ++blk) {
        // next block base (clamped: last block harmlessly re-reads itself, L2-hot)
        const int nxt = (blk + 1 < NBLK ? blk + 1 : blk) * NPF;
#pragma unroll
        for (int i = 0; i < NPF; ++i) {
            float4 v = buf[i];
            buf[i] = xp[nxt + i];   // refill slot; consumed one full block later

            // off-chain q computation (independent of E)
            float q0 = fmaf(v.x, A2, C2);
            float q1 = fmaf(v.y, A2, C2);
            float q2 = fmaf(v.z, A2, C2);
            float q3 = fmaf(v.w, A2, C2);

            // 4 dependent steps: add -> rcp -> fma -> exp2
            E = __builtin_amdgcn_exp2f(fmaf(__builtin_amdgcn_rcpf(E + 1.0f), nB4, q0));
            E = __builtin_amdgcn_exp2f(fmaf(__builtin_amdgcn_rcpf(E + 1.0f), nB4, q1));
            E = __builtin_amdgcn_exp2f(fmaf(__builtin_amdgcn_rcpf(E + 1.0f), nB4, q2));
            E = __builtin_amdgcn_exp2f(fmaf(__builtin_amdgcn_rcpf(E + 1.0f), nB4, q3));
        }
    }

    // h_T = 1 - 2*rcp(E_T + 1)
    out[row] = fmaf(-2.0f, __builtin_amdgcn_rcpf(E + 1.0f), 1.0f);
}

extern "C" void kernel_launch(void* const* d_in, const int* in_sizes, int n_in,
                              void* d_out, int out_size, void* d_ws, size_t ws_size,
                              hipStream_t stream) {
    const float* x    = (const float*)d_in[0];
    const float* w_ih = (const float*)d_in[1];
    const float* w_hh = (const float*)d_in[2];
    const float* b_ih = (const float*)d_in[3];
    const float* b_hh = (const float*)d_in[4];
    float* out = (float*)d_out;

    const int B = out_size;              // 8192 rows, 1 lane per row
    dim3 grid(B / 64), block(64);
    rnn_scan_kernel<<<grid, block, 0, stream>>>(x, w_ih, w_hh, b_ih, b_hh, out);
}

// Round 2
// 206.870 us; speedup vs baseline: 1.3119x; 1.3119x over previous
//
#include <hip/hip_runtime.h>

// SimpleRNN hidden=1: h_t = tanh(a*x_t + b*h_{t-1} + c), out = h_T per row.
// B=8192 chains x T=4096 steps. Round-1 measured 76 cyc/step dependent chain
// (add -> v_rcp(~32) -> fma -> v_exp(~36)) with only 128 waves => 129 us.
//
// Round 2: parallel-in-T. C=16 chunks of L=256. Chunk c computes, from h=0:
//   G_c = chunk output, P_c = dG/dh|_0 = prod_k b*sech^2(t_k)  (exact 1st deriv)
// Contraction (|g|<=|b|<1) makes the 2nd-order residual ~ g^256 ~ 0.
// Combine: h <- G_c + P_c*h over c=0..15 (tiny kernel).
//
// E-formulation (bit-stable, absmax=0.0 in round 1): E = exp(2t),
//   r = rcp(E+1); h = 1-2r; E' = exp2(fma(r, -4b*log2e, q)), q = fma(x,A2,C2).
// Gain: g = b*(1-h^2) = (4b*r)*(1-r)  -- accumulated off the critical chain.

constexpr int T_LEN   = 4096;
constexpr int NCHUNK  = 16;
constexpr int L_STEPS = T_LEN / NCHUNK;   // 256 steps per chunk
constexpr int NV4     = L_STEPS / 4;      // 64 float4 per chunk
constexpr int NPF     = 16;               // prefetch ring: 64-step lookahead
constexpr int NBLK    = NV4 / NPF;        // 4
constexpr int B_ROWS  = 8192;

#define STEP(qv)                                                        \
    do {                                                                \
        float r_ = __builtin_amdgcn_rcpf(E + 1.0f);                     \
        P *= (fourb * r_) * (1.0f - r_);   /* off-chain gain product */ \
        E = __builtin_amdgcn_exp2f(fmaf(r_, nB4, (qv)));                \
    } while (0)

__global__ __launch_bounds__(64, 1)
void rnn_chunk_kernel(const float* __restrict__ x,
                      const float* __restrict__ w_ih,
                      const float* __restrict__ w_hh,
                      const float* __restrict__ b_ih,
                      const float* __restrict__ b_hh,
                      float* __restrict__ ws) {
    const int rg  = blockIdx.x & (B_ROWS / 64 - 1);   // 128 row-groups
    const int c   = blockIdx.x >> 7;                  // 16 chunks
    const int row = rg * 64 + threadIdx.x;

    const float a  = w_ih[0];
    const float bb = w_hh[0];
    const float cc = b_ih[0] + b_hh[0];

    const float L2E2  = 2.88539008177792681472f;  // 2*log2(e)
    const float A2    = a * L2E2;
    const float C2    = (bb + cc) * L2E2;
    const float nB4   = -(bb * L2E2 * 2.0f);      // -4b*log2(e)
    const float fourb = 4.0f * bb;

    const float4* xp = (const float4*)(x + (size_t)row * T_LEN + (size_t)c * L_STEPS);

    float4 buf[NPF];
#pragma unroll
    for (int i = 0; i < NPF; ++i) buf[i] = xp[i];

    float E = 1.0f;   // h = 0 at chunk start (linearization point)
    float P = 1.0f;   // running gain product (includes one spurious h0 factor = b)

    for (int blk = 0; blk < NBLK; ++blk) {
        const int nxt = (blk + 1 < NBLK ? blk + 1 : blk) * NPF;
#pragma unroll
        for (int i = 0; i < NPF; ++i) {
            float4 v = buf[i];
            buf[i] = xp[nxt + i];
            float q0 = fmaf(v.x, A2, C2);
            float q1 = fmaf(v.y, A2, C2);
            float q2 = fmaf(v.z, A2, C2);
            float q3 = fmaf(v.w, A2, C2);
            STEP(q0); STEP(q1); STEP(q2); STEP(q3);
        }
    }

    // Tail: h_L's r (for both G and the last gain factor); remove spurious
    // first factor g(r=0.5)=b via one rcp.
    float r = __builtin_amdgcn_rcpf(E + 1.0f);
    float G = fmaf(-2.0f, r, 1.0f);
    P *= (fourb * r) * (1.0f - r);
    P *= __builtin_amdgcn_rcpf(bb);

    ws[(size_t)(2 * c)     * B_ROWS + row] = G;
    ws[(size_t)(2 * c + 1) * B_ROWS + row] = P;
}

__global__ __launch_bounds__(64, 1)
void rnn_combine_kernel(const float* __restrict__ ws, float* __restrict__ out) {
    const int row = blockIdx.x * 64 + threadIdx.x;
    float h = 0.0f;
#pragma unroll
    for (int c = 0; c < NCHUNK; ++c) {
        float G = ws[(size_t)(2 * c)     * B_ROWS + row];
        float P = ws[(size_t)(2 * c + 1) * B_ROWS + row];
        h = fmaf(P, h, G);   // h_out = G_c + P_c * h_in
    }
    out[row] = h;
}

// ---- Fallback (exact monolithic scan from round 1) if ws is too small ----
__global__ __launch_bounds__(64, 1)
void rnn_scan_kernel(const float* __restrict__ x,
                     const float* __restrict__ w_ih,
                     const float* __restrict__ w_hh,
                     const float* __restrict__ b_ih,
                     const float* __restrict__ b_hh,
                     float* __restrict__ out) {
    const int row = blockIdx.x * 64 + threadIdx.x;
    const float a  = w_ih[0];
    const float bb = w_hh[0];
    const float cc = b_ih[0] + b_hh[0];
    const float L2E2 = 2.88539008177792681472f;
    const float A2  = a * L2E2;
    const float C2  = (bb + cc) * L2E2;
    const float nB4 = -(bb * L2E2 * 2.0f);

    const float4* xp = (const float4*)(x + (size_t)row * T_LEN);
    constexpr int FNBLK = T_LEN / 4 / NPF;
    float4 buf[NPF];
#pragma unroll
    for (int i = 0; i < NPF; ++i) buf[i] = xp[i];
    float E = 1.0f;
    for (int blk = 0; blk < FNBLK; ++blk) {
        const int nxt = (blk + 1 < FNBLK ? blk + 1 : blk) * NPF;
#pragma unroll
        for (int i = 0; i < NPF; ++i) {
            float4 v = buf[i];
            buf[i] = xp[nxt + i];
            float q0 = fmaf(v.x, A2, C2);
            float q1 = fmaf(v.y, A2, C2);
            float q2 = fmaf(v.z, A2, C2);
            float q3 = fmaf(v.w, A2, C2);
            E = __builtin_amdgcn_exp2f(fmaf(__builtin_amdgcn_rcpf(E + 1.0f), nB4, q0));
            E = __builtin_amdgcn_exp2f(fmaf(__builtin_amdgcn_rcpf(E + 1.0f), nB4, q1));
            E = __builtin_amdgcn_exp2f(fmaf(__builtin_amdgcn_rcpf(E + 1.0f), nB4, q2));
            E = __builtin_amdgcn_exp2f(fmaf(__builtin_amdgcn_rcpf(E + 1.0f), nB4, q3));
        }
    }
    out[row] = fmaf(-2.0f, __builtin_amdgcn_rcpf(E + 1.0f), 1.0f);
}

extern "C" void kernel_launch(void* const* d_in, const int* in_sizes, int n_in,
                              void* d_out, int out_size, void* d_ws, size_t ws_size,
                              hipStream_t stream) {
    const float* x    = (const float*)d_in[0];
    const float* w_ih = (const float*)d_in[1];
    const float* w_hh = (const float*)d_in[2];
    const float* b_ih = (const float*)d_in[3];
    const float* b_hh = (const float*)d_in[4];
    float* out = (float*)d_out;

    const size_t ws_needed = (size_t)2 * NCHUNK * B_ROWS * sizeof(float); // 1 MiB

    if (ws_size >= ws_needed) {
        float* ws = (float*)d_ws;
        dim3 grid1((B_ROWS / 64) * NCHUNK), block(64);   // 2048 blocks
        rnn_chunk_kernel<<<grid1, block, 0, stream>>>(x, w_ih, w_hh, b_ih, b_hh, ws);
        dim3 grid2(B_ROWS / 64);                          // 128 blocks
        rnn_combine_kernel<<<grid2, block, 0, stream>>>(ws, out);
    } else {
        dim3 grid(B_ROWS / 64), block(64);
        rnn_scan_kernel<<<grid, block, 0, stream>>>(x, w_ih, w_hh, b_ih, b_hh, out);
    }
}

// Round 3
// 197.489 us; speedup vs baseline: 1.3742x; 1.0475x over previous
//
#include <hip/hip_runtime.h>

// SimpleRNN hidden=1: h_t = tanh(a*x_t + b*h_{t-1} + c), out = h_T per row.
// B=8192 rows x T=4096 steps, x fp32 [B,T] row-major.
//
// Round-3 structure: ONE WAVE PER ROW. Lane c owns chunk c (64 chunks x 64
// steps). Each lane loads its 256 B chunk into 16 float4 registers -- per
// load instr the wave covers a dense 16 KiB span (DRAM-friendly streaming;
// round-2's 16KiB-strided 64B granules ran at ~2.2 TB/s effective).
//
// Per chunk (from h=0): G = chunk output, P = dF/dh|_0 = prod_k b*sech^2(t_k)
// (exact first derivative, accumulated off the critical chain).
// Combine across lanes: h <- G_c + P_c*h is an associative affine map ->
// 6-step __shfl_up inclusive scan; lane 63 holds h_T (h0=0 => G_total).
//
// E-formulation (bit-stable; absmax 0.0 in rounds 1-2): E = exp(2t),
//   r = rcp(E+1); h = 1-2r; E' = exp2(fma(r, nB4, q)); q = fma(x, A2, C2)
//   gain factor: b*(1-h^2) = (4b*r)*(1-r), taken at post-step state.

constexpr int T_LEN = 4096;
constexpr int LCH   = 64;            // steps per chunk = lanes' chunk length
constexpr int NF4   = LCH / 4;       // 16 float4 registers per lane

#define STEP_PG(qv)                                                     \
    do {                                                                \
        float r_ = __builtin_amdgcn_rcpf(E + 1.0f);                     \
        P *= (fourb * r_) * (1.0f - r_);  /* factor at previous state */\
        E = __builtin_amdgcn_exp2f(fmaf(r_, nB4, (qv)));                \
    } while (0)

__global__ __launch_bounds__(256, 4)
void rnn_row_kernel(const float* __restrict__ x,
                    const float* __restrict__ w_ih,
                    const float* __restrict__ w_hh,
                    const float* __restrict__ b_ih,
                    const float* __restrict__ b_hh,
                    float* __restrict__ out) {
    const int wave = threadIdx.x >> 6;
    const int lane = threadIdx.x & 63;
    const int row  = blockIdx.x * 4 + wave;

    const float a  = w_ih[0];
    const float bb = w_hh[0];
    const float cc = b_ih[0] + b_hh[0];

    const float L2E2  = 2.88539008177792681472f;   // 2*log2(e)
    const float A2    = a * L2E2;
    const float C2    = (bb + cc) * L2E2;
    const float nB4   = -(bb * L2E2 * 2.0f);       // -4b*log2(e)
    const float fourb = 4.0f * bb;

    // Lane c's chunk: 64 consecutive floats at row*4096 + c*64.
    const float4* xp = (const float4*)(x + (size_t)row * T_LEN + lane * LCH);

    float4 buf[NF4];
#pragma unroll
    for (int i = 0; i < NF4; ++i) buf[i] = xp[i];

    float E, P = 1.0f;

    // First step special-cased: h=0 => r=0.5 exactly; skip its gain factor
    // (factor at pre-state h_0 is not part of dF/dh and would be b -- avoid
    // the rcp(b) fixup and its b==0 hazard).
    {
        float4 v = buf[0];
        float q0 = fmaf(v.x, A2, C2);
        float q1 = fmaf(v.y, A2, C2);
        float q2 = fmaf(v.z, A2, C2);
        float q3 = fmaf(v.w, A2, C2);
        E = __builtin_amdgcn_exp2f(fmaf(0.5f, nB4, q0));
        STEP_PG(q1); STEP_PG(q2); STEP_PG(q3);
    }
#pragma unroll
    for (int i = 1; i < NF4; ++i) {
        float4 v = buf[i];
        float q0 = fmaf(v.x, A2, C2);
        float q1 = fmaf(v.y, A2, C2);
        float q2 = fmaf(v.z, A2, C2);
        float q3 = fmaf(v.w, A2, C2);
        STEP_PG(q0); STEP_PG(q1); STEP_PG(q2); STEP_PG(q3);
    }

    // Tail: G from final state; add the final state's gain factor so
    // P = prod over steps 1..64 of b*sech^2 evaluated at post-step states.
    float r = __builtin_amdgcn_rcpf(E + 1.0f);
    float G = fmaf(-2.0f, r, 1.0f);
    P *= (fourb * r) * (1.0f - r);

    // Inclusive affine scan over lanes: S_c = (P,G), compose
    // S_hi o S_lo = (P_hi*P_lo, G_hi + P_hi*G_lo).
#pragma unroll
    for (int d = 1; d < 64; d <<= 1) {
        float Pl = __shfl_up(P, d, 64);
        float Gl = __shfl_up(G, d, 64);
        if (lane >= d) {
            G = fmaf(P, Gl, G);
            P *= Pl;
        }
    }

    if (lane == 63) out[row] = G;   // h0 = 0 => h_T = G_total
}

extern "C" void kernel_launch(void* const* d_in, const int* in_sizes, int n_in,
                              void* d_out, int out_size, void* d_ws, size_t ws_size,
                              hipStream_t stream) {
    const float* x    = (const float*)d_in[0];
    const float* w_ih = (const float*)d_in[1];
    const float* w_hh = (const float*)d_in[2];
    const float* b_ih = (const float*)d_in[3];
    const float* b_hh = (const float*)d_in[4];
    float* out = (float*)d_out;

    const int B = out_size;                 // 8192 rows, one wave per row
    dim3 grid(B / 4), block(256);           // 4 waves (rows) per block
    rnn_row_kernel<<<grid, block, 0, stream>>>(x, w_ih, w_hh, b_ih, b_hh, out);
}

// Round 4
// 193.185 us; speedup vs baseline: 1.4048x; 1.0223x over previous
//
#include <hip/hip_runtime.h>

// SimpleRNN hidden=1: h_t = tanh(a*x_t + b*h_{t-1} + c), out = h_T per row.
// B=8192 rows x T=4096 steps, x fp32 [B,T] row-major.
//
// One wave per row; lane c owns chunk c (64 chunks x 64 steps).
// ROUND-4 change (only): coalesced global loads + LDS transpose.
//   R3 had lane c load its own 256-B chunk directly -> every dwordx4 had 64
//   lanes on 64 distinct 64-B lines (64 txn/instr) -> TA/request-bound
//   (~55 us, barely better than R2's strided worst case). Now the wave loads
//   its 16-KiB row with 16 fully-coalesced dwordx4 (16 txn/instr), stages to
//   LDS, and each lane reads back its contiguous chunk with ds_read_b128.
//   XOR swizzle phys = s ^ ((s>>4)&7) gives optimal 8-phase b128 on both
//   the write (lanes spread over bank-quads per p) and read (per q) sides.
//
// Math (proven absmax 0.0 in R2/R3): E = exp(2t); r = rcp(E+1); h = 1-2r;
//   E' = exp2(fma(r, nB4, q)), q = fma(x, A2, C2).
// Per chunk from h=0: G = chunk output, P = dF/dh|_0 = prod_k b*sech^2(t_k)
//   (post-step states k=1..64; first pre-state factor skipped, final state's
//   factor added at the tail). Combine across lanes: affine maps compose
//   associatively -> 6-step __shfl_up inclusive scan; lane 63 writes h_T.

constexpr int T_LEN = 4096;
constexpr int LCH   = 64;            // steps per chunk (= lane's chunk length)
constexpr int NF4   = LCH / 4;       // 16 float4 per lane

#define STEP_PG(qv)                                                     \
    do {                                                                \
        float r_ = __builtin_amdgcn_rcpf(E + 1.0f);                     \
        P *= (fourb * r_) * (1.0f - r_);                                \
        E = __builtin_amdgcn_exp2f(fmaf(r_, nB4, (qv)));                \
    } while (0)

__global__ __launch_bounds__(64)
void rnn_row_kernel(const float* __restrict__ x,
                    const float* __restrict__ w_ih,
                    const float* __restrict__ w_hh,
                    const float* __restrict__ b_ih,
                    const float* __restrict__ b_hh,
                    float* __restrict__ out) {
    __shared__ float4 sm[T_LEN / 4];          // 16 KiB: one row
    const int lane = threadIdx.x;             // 0..63
    const int row  = blockIdx.x;

    const float a  = w_ih[0];
    const float bb = w_hh[0];
    const float cc = b_ih[0] + b_hh[0];

    const float L2E2  = 2.88539008177792681472f;   // 2*log2(e)
    const float A2    = a * L2E2;
    const float C2    = (bb + cc) * L2E2;
    const float nB4   = -(bb * L2E2 * 2.0f);       // -4b*log2(e)
    const float fourb = 4.0f * bb;

    // --- Stage: 16 fully-coalesced dwordx4 (1 KiB per instr) -> LDS ---
    const float4* xp = (const float4*)(x + (size_t)row * T_LEN);
#pragma unroll
    for (int p = 0; p < 16; ++p) {
        int s = p * 64 + lane;                 // linear float4 slot in row
        sm[s ^ ((s >> 4) & 7)] = xp[s];        // bank-swizzled store
    }
    __syncthreads();

    // --- Gather own chunk: 16 x ds_read_b128, 8-phase optimal ---
    float4 buf[NF4];
#pragma unroll
    for (int q = 0; q < NF4; ++q) {
        int s = lane * NF4 + q;
        buf[q] = sm[s ^ ((s >> 4) & 7)];
    }

    // --- 64-step chunk scan from h=0, accumulating exact gain product ---
    float E, P = 1.0f;
    {
        float4 v = buf[0];
        float q0 = fmaf(v.x, A2, C2);
        float q1 = fmaf(v.y, A2, C2);
        float q2 = fmaf(v.z, A2, C2);
        float q3 = fmaf(v.w, A2, C2);
        E = __builtin_amdgcn_exp2f(fmaf(0.5f, nB4, q0));   // h=0 => r=0.5 exact
        STEP_PG(q1); STEP_PG(q2); STEP_PG(q3);
    }
#pragma unroll
    for (int i = 1; i < NF4; ++i) {
        float4 v = buf[i];
        float q0 = fmaf(v.x, A2, C2);
        float q1 = fmaf(v.y, A2, C2);
        float q2 = fmaf(v.z, A2, C2);
        float q3 = fmaf(v.w, A2, C2);
        STEP_PG(q0); STEP_PG(q1); STEP_PG(q2); STEP_PG(q3);
    }

    // Tail: G from final state; include final post-state gain factor.
    float r = __builtin_amdgcn_rcpf(E + 1.0f);
    float G = fmaf(-2.0f, r, 1.0f);
    P *= (fourb * r) * (1.0f - r);

    // --- Inclusive affine scan over lanes (chunk order) ---
#pragma unroll
    for (int d = 1; d < 64; d <<= 1) {
        float Pl = __shfl_up(P, d, 64);
        float Gl = __shfl_up(G, d, 64);
        if (lane >= d) {
            G = fmaf(P, Gl, G);
            P *= Pl;
        }
    }

    if (lane == 63) out[row] = G;   // h0 = 0 => h_T = G_total
}

extern "C" void kernel_launch(void* const* d_in, const int* in_sizes, int n_in,
                              void* d_out, int out_size, void* d_ws, size_t ws_size,
                              hipStream_t stream) {
    const float* x    = (const float*)d_in[0];
    const float* w_ih = (const float*)d_in[1];
    const float* w_hh = (const float*)d_in[2];
    const float* b_ih = (const float*)d_in[3];
    const float* b_hh = (const float*)d_in[4];
    float* out = (float*)d_out;

    const int B = out_size;                 // 8192 rows, one wave (block) per row
    dim3 grid(B), block(64);
    rnn_row_kernel<<<grid, block, 0, stream>>>(x, w_ih, w_hh, b_ih, b_hh, out);
}

// Round 6
// 183.568 us; speedup vs baseline: 1.4784x; 1.0524x over previous
//
#include <hip/hip_runtime.h>

// SimpleRNN hidden=1: h_t = tanh(a*x_t + b*h_{t-1} + c), out = h_T per row.
// B=8192 rows x T=4096 steps, x fp32 [B,T] row-major.
//
// R5/R6 structure: one 256-thread block per row. Thread t owns chunk t
// (256 chunks x 16 steps). Stage the 16-KiB row to LDS with 4 coalesced
// dwordx4 per thread (NT loads: x is single-use -> no L2/L3 allocation),
// read back per-thread chunks as ds_read_b128 through an XOR swizzle
// phys = s ^ ((s>>2)&7), which is 8-phase conflict-free on BOTH sides:
//   write s=i*256+t: quad = (t&7)^((t>>2)&7)  -> 8 distinct per 8 lanes
//   read  s=4t+q   : quad = (4(t&1)+q)^(t&7)  -> 8 distinct per 8 lanes
// (Unswizzled, the read is ~32-way conflicted: 64B stride -> 2 bank-quads.)
//
// R6 fix: __builtin_nontemporal_load needs a native vector type, not
// HIP_vector_type<float,4> -> use ext_vector_type(4) float throughout the
// staging path.
//
// Math (absmax 0.0 in R2/R3/R4): E = exp(2t); r = rcp(E+1); h = 1-2r;
//   E' = exp2(fma(r, nB4, q)), q = fma(x, A2, C2).
// Per chunk from h=0: G = chunk output, P = dF/dh|_0 = prod b*sech^2
// (post-step states; first pre-state factor skipped, final added at tail).
// Combine: affine maps compose associatively -> 6-step intra-wave shfl scan,
// then thread 0 composes the 4 wave totals (temporal order w=0..3).

constexpr int T_LEN = 4096;
constexpr int NTHR  = 256;
constexpr int CH    = T_LEN / NTHR;   // 16 steps per thread-chunk
constexpr int NF4   = CH / 4;         // 4 float4 per thread

typedef float fx4 __attribute__((ext_vector_type(4)));

__device__ __forceinline__ int swz(int s) { return s ^ ((s >> 2) & 7); }

#define STEP_PG(qv)                                                     \
    do {                                                                \
        float r_ = __builtin_amdgcn_rcpf(E + 1.0f);                     \
        P *= (fourb * r_) * (1.0f - r_);                                \
        E = __builtin_amdgcn_exp2f(fmaf(r_, nB4, (qv)));                \
    } while (0)

__global__ __launch_bounds__(NTHR)
void rnn_row_kernel(const float* __restrict__ x,
                    const float* __restrict__ w_ih,
                    const float* __restrict__ w_hh,
                    const float* __restrict__ b_ih,
                    const float* __restrict__ b_hh,
                    float* __restrict__ out) {
    __shared__ fx4 sm[T_LEN / 4];          // 16 KiB: one row
    __shared__ float wP[4], wG[4];         // per-wave affine totals

    const int tid  = threadIdx.x;
    const int lane = tid & 63;
    const int wv   = tid >> 6;
    const int row  = blockIdx.x;

    const float a  = w_ih[0];
    const float bb = w_hh[0];
    const float cc = b_ih[0] + b_hh[0];

    const float L2E2  = 2.88539008177792681472f;   // 2*log2(e)
    const float A2    = a * L2E2;
    const float C2    = (bb + cc) * L2E2;
    const float nB4   = -(bb * L2E2 * 2.0f);       // -4b*log2(e)
    const float fourb = 4.0f * bb;

    // --- Stage: 4 coalesced NT dwordx4 per thread -> swizzled LDS ---
    const fx4* xp = (const fx4*)(x + (size_t)row * T_LEN);
#pragma unroll
    for (int i = 0; i < 4; ++i) {
        int s = i * NTHR + tid;
        sm[swz(s)] = __builtin_nontemporal_load(&xp[s]);
    }
    __syncthreads();

    // --- Gather own 16-step chunk: 4 x ds_read_b128, 8-phase clean ---
    fx4 buf[NF4];
#pragma unroll
    for (int q = 0; q < NF4; ++q) buf[q] = sm[swz(tid * NF4 + q)];

    // --- 16-step chunk scan from h=0 with exact gain product ---
    float E, P = 1.0f;
    {
        fx4 v = buf[0];
        float q0 = fmaf(v.x, A2, C2);
        float q1 = fmaf(v.y, A2, C2);
        float q2 = fmaf(v.z, A2, C2);
        float q3 = fmaf(v.w, A2, C2);
        E = __builtin_amdgcn_exp2f(fmaf(0.5f, nB4, q0));  // h=0 => r=0.5 exact
        STEP_PG(q1); STEP_PG(q2); STEP_PG(q3);
    }
#pragma unroll
    for (int i = 1; i < NF4; ++i) {
        fx4 v = buf[i];
        float q0 = fmaf(v.x, A2, C2);
        float q1 = fmaf(v.y, A2, C2);
        float q2 = fmaf(v.z, A2, C2);
        float q3 = fmaf(v.w, A2, C2);
        STEP_PG(q0); STEP_PG(q1); STEP_PG(q2); STEP_PG(q3);
    }
    float r = __builtin_amdgcn_rcpf(E + 1.0f);
    float G = fmaf(-2.0f, r, 1.0f);
    P *= (fourb * r) * (1.0f - r);

    // --- Intra-wave inclusive affine scan (chunk order = lane order) ---
#pragma unroll
    for (int d = 1; d < 64; d <<= 1) {
        float Pl = __shfl_up(P, d, 64);
        float Gl = __shfl_up(G, d, 64);
        if (lane >= d) {
            G = fmaf(P, Gl, G);
            P *= Pl;
        }
    }
    if (lane == 63) { wP[wv] = P; wG[wv] = G; }
    __syncthreads();

    // --- Cross-wave composition, temporal order w=0..3; h0 = 0 ---
    if (tid == 0) {
        float h = wG[0];
        h = fmaf(wP[1], h, wG[1]);
        h = fmaf(wP[2], h, wG[2]);
        h = fmaf(wP[3], h, wG[3]);
        out[row] = h;
    }
}

extern "C" void kernel_launch(void* const* d_in, const int* in_sizes, int n_in,
                              void* d_out, int out_size, void* d_ws, size_t ws_size,
                              hipStream_t stream) {
    const float* x    = (const float*)d_in[0];
    const float* w_ih = (const float*)d_in[1];
    const float* w_hh = (const float*)d_in[2];
    const float* b_ih = (const float*)d_in[3];
    const float* b_hh = (const float*)d_in[4];
    float* out = (float*)d_out;

    const int B = out_size;                 // 8192 rows, one block per row
    dim3 grid(B), block(NTHR);
    rnn_row_kernel<<<grid, block, 0, stream>>>(x, w_ih, w_hh, b_ih, b_hh, out);
}